// Round 6
// baseline (271.434 us; speedup 1.0000x reference)
//
#include <hip/hip_runtime.h>

#define N_NODES 50000
#define N_EDGES 800000
#define F_IN    128
#define HID     32
#define HEADS   4
#define OUT_C   16

#define NBKT 196      // buckets = dst>>8 ; 196*256 = 50176 >= N_NODES
#define CAP  5120     // per-bucket capacity; mean 4082
#define EPB  4096     // edges per bucketA block; 196 blocks cover 802816
#define NB64 782      // ceil(N_NODES/64)

// bf16 helpers (RNE)
__device__ __forceinline__ unsigned short f2bf(float f) {
    unsigned int u = __float_as_uint(f);
    u += 0x7FFFu + ((u >> 16) & 1u);
    return (unsigned short)(u >> 16);
}
__device__ __forceinline__ float bf_lo(unsigned int u) { return __uint_as_float(u << 16); }
__device__ __forceinline__ float bf_hi(unsigned int u) { return __uint_as_float(u & 0xFFFF0000u); }
__device__ __forceinline__ float bf2f(unsigned short s) {
    return __uint_as_float(((unsigned int)s) << 16);
}

__device__ __forceinline__ float edge_w(float asv, float adv) {
    float v = asv + adv;
    v = (v > 0.f) ? v : 0.2f * v;        // leaky_relu(0.2)
    return __expf(v);                    // softmax shift-invariant; logits O(1)
}

// ================================================================ F1 = k_emb (h0 = x@Wemb+bemb) ∪ bucketA
__global__ __launch_bounds__(256) void k_F1(const float* __restrict__ x,
                                            const float* __restrict__ Wemb,
                                            const float* __restrict__ bemb,
                                            float* __restrict__ h0,
                                            const int* __restrict__ ei,
                                            int* __restrict__ gcnt,
                                            unsigned int* __restrict__ pairs) {
    __shared__ float xs[64][132];
    __shared__ float Wl[F_IN][HID];
    __shared__ float bl[HID];
    __shared__ int hist[NBKT];
    __shared__ int base[NBKT];
    int t = threadIdx.x;
    if (blockIdx.x < NB64) {
        // ---------------- emb GEMM ----------------
        int node0 = blockIdx.x * 64;
        if (t < HID) bl[t] = bemb[t];
        #pragma unroll
        for (int it = 0; it < 4; it++) {
            int idx = it * 256 + t;
            *(float4*)((float*)Wl + idx * 4) = *(const float4*)(Wemb + idx * 4);
        }
        #pragma unroll
        for (int it = 0; it < 8; it++) {
            int idx = it * 256 + t;
            int row = idx >> 5, c4 = idx & 31;
            float4 v = make_float4(0.f, 0.f, 0.f, 0.f);
            if (node0 + row < N_NODES) v = *(const float4*)(x + (size_t)(node0 + row) * F_IN + c4 * 4);
            *(float4*)&xs[row][c4 * 4] = v;
        }
        __syncthreads();
        int c = t & 7, g = t >> 3;
        float acc[2][4] = {};
        for (int k = 0; k < F_IN; k++) {
            float4 w4 = *(const float4*)&Wl[k][c * 4];
            #pragma unroll
            for (int n = 0; n < 2; n++) {
                float xv = xs[g * 2 + n][k];
                acc[n][0] += xv * w4.x; acc[n][1] += xv * w4.y;
                acc[n][2] += xv * w4.z; acc[n][3] += xv * w4.w;
            }
        }
        #pragma unroll
        for (int n = 0; n < 2; n++) {
            int node = node0 + g * 2 + n;
            if (node < N_NODES) {
                float4 o = make_float4(acc[n][0] + bl[c * 4], acc[n][1] + bl[c * 4 + 1],
                                       acc[n][2] + bl[c * 4 + 2], acc[n][3] + bl[c * 4 + 3]);
                *(float4*)(h0 + (size_t)node * HID + c * 4) = o;
            }
        }
    } else {
        // ---------------- bucketA: scatter (src<<8|dst&255) into bucket regions ----------------
        int e0 = (blockIdx.x - NB64) * EPB;
        for (int i = t; i < NBKT; i += 256) hist[i] = 0;
        __syncthreads();
        unsigned int p[16];
        int bb[16];
        #pragma unroll
        for (int i = 0; i < 16; i++) {
            int e = e0 + i * 256 + t;
            bb[i] = -1;
            if (e < N_EDGES) {
                int s = ei[e], d = ei[N_EDGES + e];
                p[i] = ((unsigned int)s << 8) | (unsigned int)(d & 255);
                bb[i] = d >> 8;
                atomicAdd(&hist[bb[i]], 1);
            }
        }
        __syncthreads();
        for (int i = t; i < NBKT; i += 256) {
            int c = hist[i];
            base[i] = i * CAP + (c ? atomicAdd(&gcnt[i], c) : 0);
            hist[i] = 0;   // reuse as cursor
        }
        __syncthreads();
        #pragma unroll
        for (int i = 0; i < 16; i++) {
            if (bb[i] >= 0) {
                int off = atomicAdd(&hist[bb[i]], 1);
                pairs[base[bb[i]] + off] = p[i];
            }
        }
    }
}

// ================================================================ F2 = h1f (h1=h0@W1, bf16 + alpha dots) ∪ bucketB
__global__ __launch_bounds__(256) void k_F2(const float* __restrict__ h0,
                                            const float* __restrict__ W1,
                                            const float* __restrict__ a_src,
                                            const float* __restrict__ a_dst,
                                            unsigned short* __restrict__ h1,
                                            float* __restrict__ as, float* __restrict__ ad,
                                            const unsigned int* __restrict__ pairs,
                                            const int* __restrict__ gcnt,
                                            int* __restrict__ rowptr,
                                            int* __restrict__ esrc) {
    __shared__ float xs[64][36];
    __shared__ float Wl[HID][128];
    __shared__ int cnt[256];
    __shared__ int cur[256];
    __shared__ int wsum[4];
    int t = threadIdx.x;
    if (blockIdx.x < NB64) {
        // ---------------- h1 GEMM + fused alpha1 ----------------
        int node0 = blockIdx.x * 64;
        #pragma unroll
        for (int it = 0; it < 4; it++) {
            int idx = it * 256 + t;
            *(float4*)((float*)Wl + idx * 4) = *(const float4*)(W1 + idx * 4);
        }
        #pragma unroll
        for (int it = 0; it < 2; it++) {
            int idx = it * 256 + t;
            int row = idx >> 3, c4 = idx & 7;
            float4 v = make_float4(0.f, 0.f, 0.f, 0.f);
            if (node0 + row < N_NODES) v = *(const float4*)(h0 + (size_t)(node0 + row) * HID + c4 * 4);
            *(float4*)&xs[row][c4 * 4] = v;
        }
        __syncthreads();
        int c = t & 31, g = t >> 5;
        float acc[8][4] = {};
        for (int k = 0; k < HID; k++) {
            float4 w4 = *(const float4*)&Wl[k][c * 4];
            #pragma unroll
            for (int n = 0; n < 8; n++) {
                float xv = xs[g * 8 + n][k];
                acc[n][0] += xv * w4.x; acc[n][1] += xv * w4.y;
                acc[n][2] += xv * w4.z; acc[n][3] += xv * w4.w;
            }
        }
        float4 av = *(const float4*)(a_src + c * 4);
        float4 dv = *(const float4*)(a_dst + c * 4);
        float ps[8], pd[8];
        #pragma unroll
        for (int n = 0; n < 8; n++) {
            int node = node0 + g * 8 + n;
            if (node < N_NODES) {
                ushort4 o;
                o.x = f2bf(acc[n][0]); o.y = f2bf(acc[n][1]);
                o.z = f2bf(acc[n][2]); o.w = f2bf(acc[n][3]);
                *(ushort4*)(h1 + (size_t)node * 128 + c * 4) = o;
            }
            ps[n] = acc[n][0] * av.x + acc[n][1] * av.y + acc[n][2] * av.z + acc[n][3] * av.w;
            pd[n] = acc[n][0] * dv.x + acc[n][1] * dv.y + acc[n][2] * dv.z + acc[n][3] * dv.w;
        }
        #pragma unroll
        for (int mask = 1; mask <= 4; mask <<= 1) {
            #pragma unroll
            for (int n = 0; n < 8; n++) {
                ps[n] += __shfl_xor(ps[n], mask, 64);
                pd[n] += __shfl_xor(pd[n], mask, 64);
            }
        }
        if ((c & 7) == 0) {
            int hh = c >> 3;
            #pragma unroll
            for (int n = 0; n < 8; n++) {
                int node = node0 + g * 8 + n;
                if (node < N_NODES) { as[node * 4 + hh] = ps[n]; ad[node * 4 + hh] = pd[n]; }
            }
        }
    } else {
        // ---------------- bucketB: local CSR + esrc scatter ----------------
        int b = blockIdx.x - NB64;
        int lane = t & 63, wv = t >> 6;
        // bbase = sum of gcnt[0..b-1] (block reduction)
        int v0 = (t < NBKT && t < b) ? gcnt[t] : 0;
        #pragma unroll
        for (int mask = 1; mask < 64; mask <<= 1) v0 += __shfl_xor(v0, mask, 64);
        if (lane == 0) wsum[wv] = v0;
        __syncthreads();
        int base = wsum[0] + wsum[1] + wsum[2] + wsum[3];
        int n0 = b << 8;
        int cntb = gcnt[b];
        int s0 = b * CAP;
        cnt[t] = 0;
        __syncthreads();
        for (int i = t; i < cntb; i += 256) atomicAdd(&cnt[pairs[s0 + i] & 255], 1);
        __syncthreads();
        int v = cnt[t], x = v;
        #pragma unroll
        for (int off = 1; off < 64; off <<= 1) { int y = __shfl_up(x, off, 64); if (lane >= off) x += y; }
        __syncthreads();               // wsum reused
        if (lane == 63) wsum[wv] = x;
        __syncthreads();
        int add = 0;
        for (int j = 0; j < wv; j++) add += wsum[j];
        int excl = base + (x - v) + add;
        cur[t] = excl;
        if (n0 + t < N_NODES) rowptr[n0 + t] = excl;
        if (b == 0 && t == 0) rowptr[N_NODES] = N_EDGES;
        __syncthreads();
        for (int i = t; i < cntb; i += 256) {
            unsigned int p = pairs[s0 + i];
            int pos = atomicAdd(&cur[p & 255], 1);
            esrc[pos] = (int)(p >> 8);
        }
    }
}

// ================================================================ h2 = out1(bf16) @ W2 (bf16 out) + fused alpha2
__global__ __launch_bounds__(256) void k_h2f(const unsigned int* __restrict__ hin,  // bf16x2, 64/row
                                             const float* __restrict__ W2,
                                             const float* __restrict__ a_src,
                                             const float* __restrict__ a_dst,
                                             unsigned short* __restrict__ h2,
                                             float* __restrict__ as, float* __restrict__ ad) {
    __shared__ float xs[64][132];
    __shared__ float Wl[128][64];
    int t = threadIdx.x;
    int node0 = blockIdx.x * 64;
    #pragma unroll
    for (int it = 0; it < 8; it++) {
        int idx = it * 256 + t;
        *(float4*)((float*)Wl + idx * 4) = *(const float4*)(W2 + idx * 4);
    }
    #pragma unroll
    for (int it = 0; it < 8; it++) {
        int idx = it * 256 + t;                 // float4-slot: row, 4 channels
        int row = idx >> 5, c4 = idx & 31;
        float4 v = make_float4(0.f, 0.f, 0.f, 0.f);
        if (node0 + row < N_NODES) {
            uint2 u = *(const uint2*)(hin + (size_t)(node0 + row) * 64 + c4 * 2);
            v = make_float4(bf_lo(u.x), bf_hi(u.x), bf_lo(u.y), bf_hi(u.y));
        }
        *(float4*)&xs[row][c4 * 4] = v;
    }
    __syncthreads();
    int c = t & 15, g = t >> 4;
    float acc[4][4] = {};
    for (int k = 0; k < 128; k++) {
        float4 w4 = *(const float4*)&Wl[k][c * 4];
        #pragma unroll
        for (int n = 0; n < 4; n++) {
            float xv = xs[g * 4 + n][k];
            acc[n][0] += xv * w4.x; acc[n][1] += xv * w4.y;
            acc[n][2] += xv * w4.z; acc[n][3] += xv * w4.w;
        }
    }
    float4 av = *(const float4*)(a_src + c * 4);
    float4 dv = *(const float4*)(a_dst + c * 4);
    float ps[4], pd[4];
    #pragma unroll
    for (int n = 0; n < 4; n++) {
        int node = node0 + g * 4 + n;
        if (node < N_NODES) {
            ushort4 o;
            o.x = f2bf(acc[n][0]); o.y = f2bf(acc[n][1]);
            o.z = f2bf(acc[n][2]); o.w = f2bf(acc[n][3]);
            *(ushort4*)(h2 + (size_t)node * 64 + c * 4) = o;
        }
        ps[n] = acc[n][0] * av.x + acc[n][1] * av.y + acc[n][2] * av.z + acc[n][3] * av.w;
        pd[n] = acc[n][0] * dv.x + acc[n][1] * dv.y + acc[n][2] * dv.z + acc[n][3] * dv.w;
    }
    #pragma unroll
    for (int mask = 1; mask <= 2; mask <<= 1) {
        #pragma unroll
        for (int n = 0; n < 4; n++) {
            ps[n] += __shfl_xor(ps[n], mask, 64);
            pd[n] += __shfl_xor(pd[n], mask, 64);
        }
    }
    if ((c & 3) == 0) {
        int hh = c >> 2;
        #pragma unroll
        for (int n = 0; n < 4; n++) {
            int node = node0 + g * 4 + n;
            if (node < N_NODES) { as[node * 4 + hh] = ps[n]; ad[node * 4 + hh] = pd[n]; }
        }
    }
}

// ================================================================ layer-1 gather: 8-deep MLP, bf16 in/out
__global__ __launch_bounds__(256) void k_gather1(const int* __restrict__ esrc,
                                                 const int* __restrict__ rowptr,
                                                 const unsigned int* __restrict__ h1,   // bf16x2
                                                 const float* __restrict__ as,
                                                 const float* __restrict__ ad,
                                                 const float* __restrict__ b1,
                                                 unsigned int* __restrict__ out1) {    // bf16x2
    int t = threadIdx.x;
    int node = blockIdx.x * 4 + (t >> 6);
    int lane = t & 63;
    int head = lane >> 4;
    int widx = lane & 31;
    int h4 = widx & 3;                 // head this lane's w covers
    int j8 = widx >> 2;                // edge slot 0..7
    int beg = rowptr[node], end = rowptr[node + 1];
    float ad_w = ad[node * 4 + h4];
    float ax = 0.f, ay = 0.f, s = 0.f;
    for (int k = beg; k < end; k += 8) {
        int sm = esrc[min(k + j8, end - 1)];
        float wm = edge_w(as[sm * 4 + h4], ad_w);
        #pragma unroll
        for (int j = 0; j < 8; j++) {
            if (k + j < end) {                       // wave-uniform guard
                int sj = __shfl(sm, 4 * j, 64);
                float wj = __shfl(wm, 4 * j + head, 64);
                unsigned int u = h1[(size_t)sj * 64 + lane];
                ax += bf_lo(u) * wj;
                ay += bf_hi(u) * wj;
                s += wj;
            }
        }
    }
    float rs = 1.0f / (s + 1e-16f);
    float2 bv = *(const float2*)(b1 + 2 * lane);
    float vx = ax * rs + bv.x;
    float vy = ay * rs + bv.y;
    vx = (vx > 0.f) ? vx : (__expf(vx) - 1.0f);   // ELU
    vy = (vy > 0.f) ? vy : (__expf(vy) - 1.0f);
    out1[(size_t)node * 64 + lane] = ((unsigned int)f2bf(vy) << 16) | (unsigned int)f2bf(vx);
}

// ================================================================ layer-2 gather + head-mean + b2 + log_softmax
__global__ __launch_bounds__(256) void k_gather2(const int* __restrict__ esrc,
                                                 const int* __restrict__ rowptr,
                                                 const unsigned short* __restrict__ h2,  // bf16
                                                 const float* __restrict__ as,
                                                 const float* __restrict__ ad,
                                                 const float* __restrict__ b2,
                                                 float* __restrict__ out) {
    int t = threadIdx.x;
    int node = blockIdx.x * 4 + (t >> 6);
    int lane = t & 63;
    int head = lane >> 4, c = lane & 15;
    int widx = lane & 31;
    int h4 = widx & 3;
    int j8 = widx >> 2;
    int beg = rowptr[node], end = rowptr[node + 1];
    float ad_w = ad[node * 4 + h4];
    float acc = 0.f, s = 0.f;
    for (int k = beg; k < end; k += 8) {
        int sm = esrc[min(k + j8, end - 1)];
        float wm = edge_w(as[sm * 4 + h4], ad_w);
        #pragma unroll
        for (int j = 0; j < 8; j++) {
            if (k + j < end) {
                int sj = __shfl(sm, 4 * j, 64);
                float wj = __shfl(wm, 4 * j + head, 64);
                acc += bf2f(h2[(size_t)sj * 64 + lane]) * wj;
                s += wj;
            }
        }
    }
    float v = acc * (1.0f / (s + 1e-16f));
    v += __shfl_xor(v, 16, 64);          // mean over 4 heads
    v += __shfl_xor(v, 32, 64);
    v = v * 0.25f + b2[c];
    float m = v;                         // log_softmax over 16 classes
    #pragma unroll
    for (int mask = 1; mask < 16; mask <<= 1) m = fmaxf(m, __shfl_xor(m, mask, 64));
    float ex = __expf(v - m);
    float se = ex;
    #pragma unroll
    for (int mask = 1; mask < 16; mask <<= 1) se += __shfl_xor(se, mask, 64);
    float res = (v - m) - __logf(se);
    if (lane < 16) out[(size_t)node * 16 + lane] = res;
}

// ================================================================ host
extern "C" void kernel_launch(void* const* d_in, const int* in_sizes, int n_in,
                              void* d_out, int out_size, void* d_ws, size_t ws_size,
                              hipStream_t stream) {
    const float* x      = (const float*)d_in[0];
    const int*   ei     = (const int*)d_in[1];
    const float* Wemb   = (const float*)d_in[2];
    const float* bemb   = (const float*)d_in[3];
    const float* W1     = (const float*)d_in[4];
    const float* a_src1 = (const float*)d_in[5];
    const float* a_dst1 = (const float*)d_in[6];
    const float* b1     = (const float*)d_in[7];
    const float* W2     = (const float*)d_in[8];
    const float* a_src2 = (const float*)d_in[9];
    const float* a_dst2 = (const float*)d_in[10];
    const float* b2     = (const float*)d_in[11];
    float* out = (float*)d_out;

    char* ws = (char*)d_ws;
    size_t off = 0;
    auto alloc = [&](size_t bytes) { char* p = ws + off; off += (bytes + 255) & ~size_t(255); return p; };
    unsigned short* h1b   = (unsigned short*)alloc((size_t)N_NODES * 128 * 2);  // h2b [N,64] overlays front
    unsigned int*   out1b = (unsigned int*)alloc((size_t)N_NODES * 64 * 4);     // bf16x2 [N,128]
    float*        h0    = (float*)alloc((size_t)N_NODES * HID * 4);
    int*          esrc  = (int*)alloc((size_t)N_EDGES * 4 + 64);
    unsigned int* pairs = (unsigned int*)alloc((size_t)NBKT * CAP * 4);
    float* as     = (float*)alloc((size_t)N_NODES * 4 * 4);
    float* ad     = (float*)alloc((size_t)N_NODES * 4 * 4);
    int*   rowptr = (int*)alloc((size_t)(N_NODES + 1) * 4);
    int*   gcnt   = (int*)alloc((size_t)NBKT * 4);
    unsigned short* h2b = h1b;     // h1b dead after gather1

    const int GB = N_NODES / 4;    // 12500

    hipMemsetAsync(gcnt, 0, (size_t)NBKT * 4, stream);
    // F1: emb GEMM ∪ bucketA (independent, overlapped)
    k_F1<<<NB64 + NBKT, 256, 0, stream>>>(x, Wemb, bemb, h0, ei, gcnt, pairs);
    // F2: h1 GEMM + alpha1 ∪ bucketB (independent, overlapped)
    k_F2<<<NB64 + NBKT, 256, 0, stream>>>(h0, W1, a_src1, a_dst1, h1b, as, ad,
                                          pairs, gcnt, rowptr, esrc);
    k_gather1<<<GB, 256, 0, stream>>>(esrc, rowptr, (const unsigned int*)h1b, as, ad, b1, out1b);
    k_h2f<<<NB64, 256, 0, stream>>>((const unsigned int*)out1b, W2, a_src2, a_dst2, h2b, as, ad);
    k_gather2<<<GB, 256, 0, stream>>>(esrc, rowptr, h2b, as, ad, b2, out);
}

// Round 7
// 214.853 us; speedup vs baseline: 1.2633x; 1.2633x over previous
//
#include <hip/hip_runtime.h>

#define N_NODES 50000
#define N_EDGES 800000
#define F_IN    128
#define HID     32
#define HEADS   4
#define OUT_C   16

#define NBKT 196      // buckets = dst>>8 ; 196*256 = 50176 >= N_NODES
#define CAP  5120     // per-bucket capacity; mean 4082
#define EPB  4096     // edges per bucketA block; 196 blocks cover 802816
#define NB64 782      // ceil(N_NODES/64)

// bf16 helpers (RNE)
__device__ __forceinline__ unsigned short f2bf(float f) {
    unsigned int u = __float_as_uint(f);
    u += 0x7FFFu + ((u >> 16) & 1u);
    return (unsigned short)(u >> 16);
}
__device__ __forceinline__ float bf_lo(unsigned int u) { return __uint_as_float(u << 16); }
__device__ __forceinline__ float bf_hi(unsigned int u) { return __uint_as_float(u & 0xFFFF0000u); }
__device__ __forceinline__ float bf2f(unsigned short s) {
    return __uint_as_float(((unsigned int)s) << 16);
}

__device__ __forceinline__ float edge_w(float asv, float adv) {
    float v = asv + adv;
    v = (v > 0.f) ? v : 0.2f * v;        // leaky_relu(0.2)
    return __expf(v);                    // softmax shift-invariant; logits O(1)
}

// ================================================================ F1 = k_emb (h0 = x@Wemb+bemb) ∪ bucketA
__global__ __launch_bounds__(256) void k_F1(const float* __restrict__ x,
                                            const float* __restrict__ Wemb,
                                            const float* __restrict__ bemb,
                                            float* __restrict__ h0,
                                            const int* __restrict__ ei,
                                            int* __restrict__ gcnt,
                                            unsigned int* __restrict__ pairs) {
    __shared__ float xs[64][132];
    __shared__ float Wl[F_IN][HID];
    __shared__ float bl[HID];
    __shared__ int hist[NBKT];
    __shared__ int base[NBKT];
    int t = threadIdx.x;
    if (blockIdx.x < NB64) {
        int node0 = blockIdx.x * 64;
        if (t < HID) bl[t] = bemb[t];
        #pragma unroll
        for (int it = 0; it < 4; it++) {
            int idx = it * 256 + t;
            *(float4*)((float*)Wl + idx * 4) = *(const float4*)(Wemb + idx * 4);
        }
        #pragma unroll
        for (int it = 0; it < 8; it++) {
            int idx = it * 256 + t;
            int row = idx >> 5, c4 = idx & 31;
            float4 v = make_float4(0.f, 0.f, 0.f, 0.f);
            if (node0 + row < N_NODES) v = *(const float4*)(x + (size_t)(node0 + row) * F_IN + c4 * 4);
            *(float4*)&xs[row][c4 * 4] = v;
        }
        __syncthreads();
        int c = t & 7, g = t >> 3;
        float acc[2][4] = {};
        for (int k = 0; k < F_IN; k++) {
            float4 w4 = *(const float4*)&Wl[k][c * 4];
            #pragma unroll
            for (int n = 0; n < 2; n++) {
                float xv = xs[g * 2 + n][k];
                acc[n][0] += xv * w4.x; acc[n][1] += xv * w4.y;
                acc[n][2] += xv * w4.z; acc[n][3] += xv * w4.w;
            }
        }
        #pragma unroll
        for (int n = 0; n < 2; n++) {
            int node = node0 + g * 2 + n;
            if (node < N_NODES) {
                float4 o = make_float4(acc[n][0] + bl[c * 4], acc[n][1] + bl[c * 4 + 1],
                                       acc[n][2] + bl[c * 4 + 2], acc[n][3] + bl[c * 4 + 3]);
                *(float4*)(h0 + (size_t)node * HID + c * 4) = o;
            }
        }
    } else {
        int e0 = (blockIdx.x - NB64) * EPB;
        for (int i = t; i < NBKT; i += 256) hist[i] = 0;
        __syncthreads();
        unsigned int p[16];
        int bb[16];
        #pragma unroll
        for (int i = 0; i < 16; i++) {
            int e = e0 + i * 256 + t;
            bb[i] = -1;
            if (e < N_EDGES) {
                int s = ei[e], d = ei[N_EDGES + e];
                p[i] = ((unsigned int)s << 8) | (unsigned int)(d & 255);
                bb[i] = d >> 8;
                atomicAdd(&hist[bb[i]], 1);
            }
        }
        __syncthreads();
        for (int i = t; i < NBKT; i += 256) {
            int c = hist[i];
            base[i] = i * CAP + (c ? atomicAdd(&gcnt[i], c) : 0);
            hist[i] = 0;
        }
        __syncthreads();
        #pragma unroll
        for (int i = 0; i < 16; i++) {
            if (bb[i] >= 0) {
                int off = atomicAdd(&hist[bb[i]], 1);
                pairs[base[bb[i]] + off] = p[i];
            }
        }
    }
}

// ================================================================ F2 = h1f (h1=h0@W1, bf16 + alpha dots) ∪ bucketB
__global__ __launch_bounds__(256) void k_F2(const float* __restrict__ h0,
                                            const float* __restrict__ W1,
                                            const float* __restrict__ a_src,
                                            const float* __restrict__ a_dst,
                                            unsigned short* __restrict__ h1,
                                            float* __restrict__ as, float* __restrict__ ad,
                                            const unsigned int* __restrict__ pairs,
                                            const int* __restrict__ gcnt,
                                            int* __restrict__ rowptr,
                                            int* __restrict__ esrc) {
    __shared__ float xs[64][36];
    __shared__ float Wl[HID][128];
    __shared__ int cnt[256];
    __shared__ int cur[256];
    __shared__ int wsum[4];
    int t = threadIdx.x;
    if (blockIdx.x < NB64) {
        int node0 = blockIdx.x * 64;
        #pragma unroll
        for (int it = 0; it < 4; it++) {
            int idx = it * 256 + t;
            *(float4*)((float*)Wl + idx * 4) = *(const float4*)(W1 + idx * 4);
        }
        #pragma unroll
        for (int it = 0; it < 2; it++) {
            int idx = it * 256 + t;
            int row = idx >> 3, c4 = idx & 7;
            float4 v = make_float4(0.f, 0.f, 0.f, 0.f);
            if (node0 + row < N_NODES) v = *(const float4*)(h0 + (size_t)(node0 + row) * HID + c4 * 4);
            *(float4*)&xs[row][c4 * 4] = v;
        }
        __syncthreads();
        int c = t & 31, g = t >> 5;
        float acc[8][4] = {};
        for (int k = 0; k < HID; k++) {
            float4 w4 = *(const float4*)&Wl[k][c * 4];
            #pragma unroll
            for (int n = 0; n < 8; n++) {
                float xv = xs[g * 8 + n][k];
                acc[n][0] += xv * w4.x; acc[n][1] += xv * w4.y;
                acc[n][2] += xv * w4.z; acc[n][3] += xv * w4.w;
            }
        }
        float4 av = *(const float4*)(a_src + c * 4);
        float4 dv = *(const float4*)(a_dst + c * 4);
        float ps[8], pd[8];
        #pragma unroll
        for (int n = 0; n < 8; n++) {
            int node = node0 + g * 8 + n;
            if (node < N_NODES) {
                ushort4 o;
                o.x = f2bf(acc[n][0]); o.y = f2bf(acc[n][1]);
                o.z = f2bf(acc[n][2]); o.w = f2bf(acc[n][3]);
                *(ushort4*)(h1 + (size_t)node * 128 + c * 4) = o;
            }
            ps[n] = acc[n][0] * av.x + acc[n][1] * av.y + acc[n][2] * av.z + acc[n][3] * av.w;
            pd[n] = acc[n][0] * dv.x + acc[n][1] * dv.y + acc[n][2] * dv.z + acc[n][3] * dv.w;
        }
        #pragma unroll
        for (int mask = 1; mask <= 4; mask <<= 1) {
            #pragma unroll
            for (int n = 0; n < 8; n++) {
                ps[n] += __shfl_xor(ps[n], mask, 64);
                pd[n] += __shfl_xor(pd[n], mask, 64);
            }
        }
        if ((c & 7) == 0) {
            int hh = c >> 3;
            #pragma unroll
            for (int n = 0; n < 8; n++) {
                int node = node0 + g * 8 + n;
                if (node < N_NODES) { as[node * 4 + hh] = ps[n]; ad[node * 4 + hh] = pd[n]; }
            }
        }
    } else {
        int b = blockIdx.x - NB64;
        int lane = t & 63, wv = t >> 6;
        int v0 = (t < NBKT && t < b) ? gcnt[t] : 0;
        #pragma unroll
        for (int mask = 1; mask < 64; mask <<= 1) v0 += __shfl_xor(v0, mask, 64);
        if (lane == 0) wsum[wv] = v0;
        __syncthreads();
        int base = wsum[0] + wsum[1] + wsum[2] + wsum[3];
        int n0 = b << 8;
        int cntb = gcnt[b];
        int s0 = b * CAP;
        cnt[t] = 0;
        __syncthreads();
        for (int i = t; i < cntb; i += 256) atomicAdd(&cnt[pairs[s0 + i] & 255], 1);
        __syncthreads();
        int v = cnt[t], x = v;
        #pragma unroll
        for (int off = 1; off < 64; off <<= 1) { int y = __shfl_up(x, off, 64); if (lane >= off) x += y; }
        __syncthreads();
        if (lane == 63) wsum[wv] = x;
        __syncthreads();
        int add = 0;
        for (int j = 0; j < wv; j++) add += wsum[j];
        int excl = base + (x - v) + add;
        cur[t] = excl;
        if (n0 + t < N_NODES) rowptr[n0 + t] = excl;
        if (b == 0 && t == 0) rowptr[N_NODES] = N_EDGES;
        __syncthreads();
        for (int i = t; i < cntb; i += 256) {
            unsigned int p = pairs[s0 + i];
            int pos = atomicAdd(&cur[p & 255], 1);
            esrc[pos] = (int)(p >> 8);
        }
    }
}

// ================================================================ h2 = out1(bf16) @ W2 (bf16 out) + fused alpha2
__global__ __launch_bounds__(256) void k_h2f(const unsigned int* __restrict__ hin,
                                             const float* __restrict__ W2,
                                             const float* __restrict__ a_src,
                                             const float* __restrict__ a_dst,
                                             unsigned short* __restrict__ h2,
                                             float* __restrict__ as, float* __restrict__ ad) {
    __shared__ float xs[64][132];
    __shared__ float Wl[128][64];
    int t = threadIdx.x;
    int node0 = blockIdx.x * 64;
    #pragma unroll
    for (int it = 0; it < 8; it++) {
        int idx = it * 256 + t;
        *(float4*)((float*)Wl + idx * 4) = *(const float4*)(W2 + idx * 4);
    }
    #pragma unroll
    for (int it = 0; it < 8; it++) {
        int idx = it * 256 + t;
        int row = idx >> 5, c4 = idx & 31;
        float4 v = make_float4(0.f, 0.f, 0.f, 0.f);
        if (node0 + row < N_NODES) {
            uint2 u = *(const uint2*)(hin + (size_t)(node0 + row) * 64 + c4 * 2);
            v = make_float4(bf_lo(u.x), bf_hi(u.x), bf_lo(u.y), bf_hi(u.y));
        }
        *(float4*)&xs[row][c4 * 4] = v;
    }
    __syncthreads();
    int c = t & 15, g = t >> 4;
    float acc[4][4] = {};
    for (int k = 0; k < 128; k++) {
        float4 w4 = *(const float4*)&Wl[k][c * 4];
        #pragma unroll
        for (int n = 0; n < 4; n++) {
            float xv = xs[g * 4 + n][k];
            acc[n][0] += xv * w4.x; acc[n][1] += xv * w4.y;
            acc[n][2] += xv * w4.z; acc[n][3] += xv * w4.w;
        }
    }
    float4 av = *(const float4*)(a_src + c * 4);
    float4 dv = *(const float4*)(a_dst + c * 4);
    float ps[4], pd[4];
    #pragma unroll
    for (int n = 0; n < 4; n++) {
        int node = node0 + g * 4 + n;
        if (node < N_NODES) {
            ushort4 o;
            o.x = f2bf(acc[n][0]); o.y = f2bf(acc[n][1]);
            o.z = f2bf(acc[n][2]); o.w = f2bf(acc[n][3]);
            *(ushort4*)(h2 + (size_t)node * 64 + c * 4) = o;
        }
        ps[n] = acc[n][0] * av.x + acc[n][1] * av.y + acc[n][2] * av.z + acc[n][3] * av.w;
        pd[n] = acc[n][0] * dv.x + acc[n][1] * dv.y + acc[n][2] * dv.z + acc[n][3] * dv.w;
    }
    #pragma unroll
    for (int mask = 1; mask <= 2; mask <<= 1) {
        #pragma unroll
        for (int n = 0; n < 4; n++) {
            ps[n] += __shfl_xor(ps[n], mask, 64);
            pd[n] += __shfl_xor(pd[n], mask, 64);
        }
    }
    if ((c & 3) == 0) {
        int hh = c >> 2;
        #pragma unroll
        for (int n = 0; n < 4; n++) {
            int node = node0 + g * 4 + n;
            if (node < N_NODES) { as[node * 4 + hh] = ps[n]; ad[node * 4 + hh] = pd[n]; }
        }
    }
}

// ================================================================ layer-1 gather: 8-deep batched loads, tail by weight-zeroing
__global__ __launch_bounds__(256) void k_gather1(const int* __restrict__ esrc,
                                                 const int* __restrict__ rowptr,
                                                 const unsigned int* __restrict__ h1,   // bf16x2
                                                 const float* __restrict__ as,
                                                 const float* __restrict__ ad,
                                                 const float* __restrict__ b1,
                                                 unsigned int* __restrict__ out1) {    // bf16x2
    int t = threadIdx.x;
    int node = blockIdx.x * 4 + (t >> 6);
    int lane = t & 63;
    int head = lane >> 4;
    int widx = lane & 31;
    int h4 = widx & 3;                 // head this lane's w covers
    int j8 = widx >> 2;                // edge slot 0..7
    int beg = rowptr[node], end = rowptr[node + 1];
    float ad_w = ad[node * 4 + h4];
    float ax = 0.f, ay = 0.f, s = 0.f;
    for (int k = beg; k < end; k += 8) {
        int idx = k + j8;
        int sm = esrc[min(idx, end - 1)];
        float wm = edge_w(as[sm * 4 + h4], ad_w);
        if (idx >= end) wm = 0.f;                 // tail masking at source lane — no inner guards
        int s0 = __shfl(sm, 0, 64),  s1 = __shfl(sm, 4, 64);
        int s2 = __shfl(sm, 8, 64),  s3 = __shfl(sm, 12, 64);
        int s4 = __shfl(sm, 16, 64), s5 = __shfl(sm, 20, 64);
        int s6 = __shfl(sm, 24, 64), s7 = __shfl(sm, 28, 64);
        unsigned int u0 = h1[(size_t)s0 * 64 + lane];
        unsigned int u1 = h1[(size_t)s1 * 64 + lane];
        unsigned int u2 = h1[(size_t)s2 * 64 + lane];
        unsigned int u3 = h1[(size_t)s3 * 64 + lane];
        unsigned int u4 = h1[(size_t)s4 * 64 + lane];
        unsigned int u5 = h1[(size_t)s5 * 64 + lane];
        unsigned int u6 = h1[(size_t)s6 * 64 + lane];
        unsigned int u7 = h1[(size_t)s7 * 64 + lane];
        float w0 = __shfl(wm, head, 64),      w1 = __shfl(wm, 4 | head, 64);
        float w2 = __shfl(wm, 8 | head, 64),  w3 = __shfl(wm, 12 | head, 64);
        float w4 = __shfl(wm, 16 | head, 64), w5 = __shfl(wm, 20 | head, 64);
        float w6 = __shfl(wm, 24 | head, 64), w7 = __shfl(wm, 28 | head, 64);
        ax += bf_lo(u0) * w0 + bf_lo(u1) * w1 + bf_lo(u2) * w2 + bf_lo(u3) * w3
            + bf_lo(u4) * w4 + bf_lo(u5) * w5 + bf_lo(u6) * w6 + bf_lo(u7) * w7;
        ay += bf_hi(u0) * w0 + bf_hi(u1) * w1 + bf_hi(u2) * w2 + bf_hi(u3) * w3
            + bf_hi(u4) * w4 + bf_hi(u5) * w5 + bf_hi(u6) * w6 + bf_hi(u7) * w7;
        s += (w0 + w1 + w2 + w3) + (w4 + w5 + w6 + w7);
    }
    float rs = 1.0f / (s + 1e-16f);
    float2 bv = *(const float2*)(b1 + 2 * lane);
    float vx = ax * rs + bv.x;
    float vy = ay * rs + bv.y;
    vx = (vx > 0.f) ? vx : (__expf(vx) - 1.0f);   // ELU
    vy = (vy > 0.f) ? vy : (__expf(vy) - 1.0f);
    out1[(size_t)node * 64 + lane] = ((unsigned int)f2bf(vy) << 16) | (unsigned int)f2bf(vx);
}

// ================================================================ layer-2 gather + head-mean + b2 + log_softmax
__global__ __launch_bounds__(256) void k_gather2(const int* __restrict__ esrc,
                                                 const int* __restrict__ rowptr,
                                                 const unsigned short* __restrict__ h2,  // bf16
                                                 const float* __restrict__ as,
                                                 const float* __restrict__ ad,
                                                 const float* __restrict__ b2,
                                                 float* __restrict__ out) {
    int t = threadIdx.x;
    int node = blockIdx.x * 4 + (t >> 6);
    int lane = t & 63;
    int head = lane >> 4, c = lane & 15;
    int widx = lane & 31;
    int h4 = widx & 3;
    int j8 = widx >> 2;
    int beg = rowptr[node], end = rowptr[node + 1];
    float ad_w = ad[node * 4 + h4];
    float acc = 0.f, s = 0.f;
    for (int k = beg; k < end; k += 8) {
        int idx = k + j8;
        int sm = esrc[min(idx, end - 1)];
        float wm = edge_w(as[sm * 4 + h4], ad_w);
        if (idx >= end) wm = 0.f;
        int s0 = __shfl(sm, 0, 64),  s1 = __shfl(sm, 4, 64);
        int s2 = __shfl(sm, 8, 64),  s3 = __shfl(sm, 12, 64);
        int s4 = __shfl(sm, 16, 64), s5 = __shfl(sm, 20, 64);
        int s6 = __shfl(sm, 24, 64), s7 = __shfl(sm, 28, 64);
        float r0 = bf2f(h2[(size_t)s0 * 64 + lane]);
        float r1 = bf2f(h2[(size_t)s1 * 64 + lane]);
        float r2 = bf2f(h2[(size_t)s2 * 64 + lane]);
        float r3 = bf2f(h2[(size_t)s3 * 64 + lane]);
        float r4 = bf2f(h2[(size_t)s4 * 64 + lane]);
        float r5 = bf2f(h2[(size_t)s5 * 64 + lane]);
        float r6 = bf2f(h2[(size_t)s6 * 64 + lane]);
        float r7 = bf2f(h2[(size_t)s7 * 64 + lane]);
        float w0 = __shfl(wm, head, 64),      w1 = __shfl(wm, 4 | head, 64);
        float w2 = __shfl(wm, 8 | head, 64),  w3 = __shfl(wm, 12 | head, 64);
        float w4 = __shfl(wm, 16 | head, 64), w5 = __shfl(wm, 20 | head, 64);
        float w6 = __shfl(wm, 24 | head, 64), w7 = __shfl(wm, 28 | head, 64);
        acc += r0 * w0 + r1 * w1 + r2 * w2 + r3 * w3 + r4 * w4 + r5 * w5 + r6 * w6 + r7 * w7;
        s += (w0 + w1 + w2 + w3) + (w4 + w5 + w6 + w7);
    }
    float v = acc * (1.0f / (s + 1e-16f));
    v += __shfl_xor(v, 16, 64);          // mean over 4 heads
    v += __shfl_xor(v, 32, 64);
    v = v * 0.25f + b2[c];
    float m = v;                         // log_softmax over 16 classes
    #pragma unroll
    for (int mask = 1; mask < 16; mask <<= 1) m = fmaxf(m, __shfl_xor(m, mask, 64));
    float ex = __expf(v - m);
    float se = ex;
    #pragma unroll
    for (int mask = 1; mask < 16; mask <<= 1) se += __shfl_xor(se, mask, 64);
    float res = (v - m) - __logf(se);
    if (lane < 16) out[(size_t)node * 16 + lane] = res;
}

// ================================================================ host
extern "C" void kernel_launch(void* const* d_in, const int* in_sizes, int n_in,
                              void* d_out, int out_size, void* d_ws, size_t ws_size,
                              hipStream_t stream) {
    const float* x      = (const float*)d_in[0];
    const int*   ei     = (const int*)d_in[1];
    const float* Wemb   = (const float*)d_in[2];
    const float* bemb   = (const float*)d_in[3];
    const float* W1     = (const float*)d_in[4];
    const float* a_src1 = (const float*)d_in[5];
    const float* a_dst1 = (const float*)d_in[6];
    const float* b1     = (const float*)d_in[7];
    const float* W2     = (const float*)d_in[8];
    const float* a_src2 = (const float*)d_in[9];
    const float* a_dst2 = (const float*)d_in[10];
    const float* b2     = (const float*)d_in[11];
    float* out = (float*)d_out;

    char* ws = (char*)d_ws;
    size_t off = 0;
    auto alloc = [&](size_t bytes) { char* p = ws + off; off += (bytes + 255) & ~size_t(255); return p; };
    unsigned short* h1b   = (unsigned short*)alloc((size_t)N_NODES * 128 * 2);  // h2b [N,64] overlays front
    unsigned int*   out1b = (unsigned int*)alloc((size_t)N_NODES * 64 * 4);     // bf16x2 [N,128]
    float*        h0    = (float*)alloc((size_t)N_NODES * HID * 4);
    int*          esrc  = (int*)alloc((size_t)N_EDGES * 4 + 64);
    unsigned int* pairs = (unsigned int*)alloc((size_t)NBKT * CAP * 4);
    float* as     = (float*)alloc((size_t)N_NODES * 4 * 4);
    float* ad     = (float*)alloc((size_t)N_NODES * 4 * 4);
    int*   rowptr = (int*)alloc((size_t)(N_NODES + 1) * 4);
    int*   gcnt   = (int*)alloc((size_t)NBKT * 4);
    unsigned short* h2b = h1b;     // h1b dead after gather1

    const int GB = N_NODES / 4;    // 12500

    hipMemsetAsync(gcnt, 0, (size_t)NBKT * 4, stream);
    k_F1<<<NB64 + NBKT, 256, 0, stream>>>(x, Wemb, bemb, h0, ei, gcnt, pairs);
    k_F2<<<NB64 + NBKT, 256, 0, stream>>>(h0, W1, a_src1, a_dst1, h1b, as, ad,
                                          pairs, gcnt, rowptr, esrc);
    k_gather1<<<GB, 256, 0, stream>>>(esrc, rowptr, (const unsigned int*)h1b, as, ad, b1, out1b);
    k_h2f<<<NB64, 256, 0, stream>>>((const unsigned int*)out1b, W2, a_src2, a_dst2, h2b, as, ad);
    k_gather2<<<GB, 256, 0, stream>>>(esrc, rowptr, h2b, as, ad, b2, out);
}